// Round 3
// baseline (56.698 us; speedup 1.0000x reference)
//
#include <hip/hip_runtime.h>
#include <hip/hip_cooperative_groups.h>

namespace cg = cooperative_groups;

#define WPAD 68   // padded LDS row stride (floats); rows stay 16B-aligned

// One cooperative dispatch. Block (b, ch) owns rows m = ch*16 .. ch*16+15.
// Phase 1: a-dot chunk-max -> wsmax[b][ch][o]
// Phase 2: amax over chunks + bias, c-GEMM (from LDS staged in phase 1), out.
__global__ __launch_bounds__(256) void pe_fused(const float* __restrict__ x,
                                                const float* __restrict__ W,
                                                const float* __restrict__ bias,
                                                float* __restrict__ wsmax,
                                                float* __restrict__ out) {
    __shared__ float W1t[64 * WPAD];   // W1t[k*WPAD+o] = W[o][k]
    __shared__ float W2t[64 * WPAD];   // W2t[k*WPAD+o] = W[o][64+k]
    __shared__ float xs[16 * WPAD];
    __shared__ float red[16 * 64];
    __shared__ float addv[64];

    const int t  = threadIdx.x;
    const int b  = blockIdx.x >> 6;
    const int ch = blockIdx.x & 63;
    const int m0 = ch << 4;

    // ---- stage both W halves transposed (32 KB) ----
    const float4* W4 = (const float4*)W;   // one W row = 32 float4
    #pragma unroll
    for (int i = 0; i < 4; ++i) {
        int id = t + 256 * i;              // 0..1023
        int o = id >> 4, q = id & 15;      // o-row, k-quad
        float4 w1 = W4[o * 32 + q];
        float4 w2 = W4[o * 32 + 16 + q];
        W1t[(4 * q + 0) * WPAD + o] = w1.x;
        W1t[(4 * q + 1) * WPAD + o] = w1.y;
        W1t[(4 * q + 2) * WPAD + o] = w1.z;
        W1t[(4 * q + 3) * WPAD + o] = w1.w;
        W2t[(4 * q + 0) * WPAD + o] = w2.x;
        W2t[(4 * q + 1) * WPAD + o] = w2.y;
        W2t[(4 * q + 2) * WPAD + o] = w2.z;
        W2t[(4 * q + 3) * WPAD + o] = w2.w;
    }
    // ---- stage x rows (4 KB) ----
    {
        const float4* x4 = (const float4*)(x + ((size_t)b * 1024 + m0) * 64);
        float4 xv = x4[t];
        *(float4*)&xs[(t >> 4) * WPAD + 4 * (t & 15)] = xv;
    }
    __syncthreads();

    const int r  = t >> 4;    // row 0..15
    const int og = t & 15;    // o-quad
    const float* xr = &xs[r * WPAD];

    // ---- phase 1: a-dot, chunk max ----
    {
        float ax = 0.f, ay = 0.f, az = 0.f, aw = 0.f;
        #pragma unroll
        for (int q = 0; q < 16; ++q) {
            float4 xq = *(const float4*)&xr[4 * q];
            float4 w0 = *(const float4*)&W1t[(4 * q + 0) * WPAD + og * 4];
            float4 w1 = *(const float4*)&W1t[(4 * q + 1) * WPAD + og * 4];
            float4 w2 = *(const float4*)&W1t[(4 * q + 2) * WPAD + og * 4];
            float4 w3 = *(const float4*)&W1t[(4 * q + 3) * WPAD + og * 4];
            ax += xq.x * w0.x; ay += xq.x * w0.y; az += xq.x * w0.z; aw += xq.x * w0.w;
            ax += xq.y * w1.x; ay += xq.y * w1.y; az += xq.y * w1.z; aw += xq.y * w1.w;
            ax += xq.z * w2.x; ay += xq.z * w2.y; az += xq.z * w2.z; aw += xq.z * w2.w;
            ax += xq.w * w3.x; ay += xq.w * w3.y; az += xq.w * w3.z; aw += xq.w * w3.w;
        }
        *(float4*)&red[r * 64 + og * 4] = make_float4(ax, ay, az, aw);
    }
    __syncthreads();
    if (t < 64) {
        float v = red[t];
        #pragma unroll
        for (int rr = 1; rr < 16; ++rr) v = fmaxf(v, red[rr * 64 + t]);
        wsmax[((size_t)(b << 6) + ch) * 64 + t] = v;
    }
    __threadfence();          // device-scope release: cross-XCD visibility (G16)
    cg::this_grid().sync();

    // ---- phase 2: amax over all 64 chunks + bias ----
    {
        const int o = t & 63, g = t >> 6;
        const float* wp = wsmax + (size_t)b * 4096 + o;
        float v = wp[(size_t)g * 64];
        #pragma unroll
        for (int s = 1; s < 16; ++s) v = fmaxf(v, wp[(size_t)(g + 4 * s) * 64]);
        red[g * 64 + o] = v;   // red safely reusable: grid.sync() block-synced us
    }
    __syncthreads();
    if (t < 64) {
        addv[t] = fmaxf(fmaxf(red[t], red[64 + t]),
                        fmaxf(red[128 + t], red[192 + t])) + bias[t];
    }
    __syncthreads();

    // ---- c-GEMM from still-resident LDS, single out write ----
    float4 add = *(const float4*)&addv[og * 4];
    float cx = add.x, cy = add.y, cz = add.z, cw = add.w;
    #pragma unroll
    for (int q = 0; q < 16; ++q) {
        float4 xq = *(const float4*)&xr[4 * q];
        float4 w0 = *(const float4*)&W2t[(4 * q + 0) * WPAD + og * 4];
        float4 w1 = *(const float4*)&W2t[(4 * q + 1) * WPAD + og * 4];
        float4 w2 = *(const float4*)&W2t[(4 * q + 2) * WPAD + og * 4];
        float4 w3 = *(const float4*)&W2t[(4 * q + 3) * WPAD + og * 4];
        cx += xq.x * w0.x; cy += xq.x * w0.y; cz += xq.x * w0.z; cw += xq.x * w0.w;
        cx += xq.y * w1.x; cy += xq.y * w1.y; cz += xq.y * w1.z; cw += xq.y * w1.w;
        cx += xq.z * w2.x; cy += xq.z * w2.y; cz += xq.z * w2.z; cw += xq.z * w2.w;
        cx += xq.w * w3.x; cy += xq.w * w3.y; cz += xq.w * w3.z; cw += xq.w * w3.w;
    }
    *(float4*)&out[((size_t)b * 1024 + m0 + r) * 64 + og * 4] =
        make_float4(cx, cy, cz, cw);
}

extern "C" void kernel_launch(void* const* d_in, const int* in_sizes, int n_in,
                              void* d_out, int out_size, void* d_ws, size_t ws_size,
                              hipStream_t stream) {
    const float* x    = (const float*)d_in[0];
    const float* W    = (const float*)d_in[1];
    const float* bias = (const float*)d_in[2];
    float* out   = (float*)d_out;
    float* wsmax = (float*)d_ws;   // 4*64*64*4 = 64 KiB used

    void* args[] = { (void*)&x, (void*)&W, (void*)&bias, (void*)&wsmax, (void*)&out };
    hipLaunchCooperativeKernel((void*)pe_fused, dim3(4 * 64), dim3(256),
                               args, 0, stream);
}

// Round 4
// 18.254 us; speedup vs baseline: 3.1060x; 3.1060x over previous
//
#include <hip/hip_runtime.h>

// One dispatch, no inter-block dependencies.
// Block (b, og) owns output columns o0=og*4 .. o0+3 for ALL 1024 rows of
// batch b:
//   amax[o] = max_n x[b,n,:]·W1[o,:]          (block-internal reduce)
//   out[b,m,o] = x[b,m,:]·W2[o,:] + amax[o] + bias[o]
// 512 threads; thread t owns rows t and t+512.
__global__ __launch_bounds__(512) void pe_onepass(const float* __restrict__ x,
                                                  const float* __restrict__ W,
                                                  const float* __restrict__ bias,
                                                  float* __restrict__ out) {
    __shared__ float red[8][4];

    const int t  = threadIdx.x;
    const int b  = blockIdx.x >> 4;
    const int og = blockIdx.x & 15;
    const int o0 = og << 2;

    const float4* x4 = (const float4*)(x + (size_t)b * 1024 * 64);
    const int r0 = t;
    const int r1 = t + 512;

    float a[2][4] = {{0.f,0.f,0.f,0.f},{0.f,0.f,0.f,0.f}};
    float c[2][4] = {{0.f,0.f,0.f,0.f},{0.f,0.f,0.f,0.f}};

    #pragma unroll
    for (int q = 0; q < 16; ++q) {
        float4 xq0 = x4[r0 * 16 + q];
        float4 xq1 = x4[r1 * 16 + q];
        float xr[2][4] = {{xq0.x, xq0.y, xq0.z, xq0.w},
                          {xq1.x, xq1.y, xq1.z, xq1.w}};
        #pragma unroll
        for (int ol = 0; ol < 4; ++ol) {
            // wave-uniform addresses -> scalar loads / L1 broadcast
            float4 w1 = *(const float4*)&W[(size_t)(o0 + ol) * 128 + 4 * q];
            float4 w2 = *(const float4*)&W[(size_t)(o0 + ol) * 128 + 64 + 4 * q];
            #pragma unroll
            for (int r = 0; r < 2; ++r) {
                a[r][ol] += xr[r][0] * w1.x + xr[r][1] * w1.y
                          + xr[r][2] * w1.z + xr[r][3] * w1.w;
                c[r][ol] += xr[r][0] * w2.x + xr[r][1] * w2.y
                          + xr[r][2] * w2.z + xr[r][3] * w2.w;
            }
        }
    }

    // ---- block-wide max over all 1024 rows, per ol ----
    float am[4];
    #pragma unroll
    for (int ol = 0; ol < 4; ++ol) am[ol] = fmaxf(a[0][ol], a[1][ol]);
    #pragma unroll
    for (int s = 32; s > 0; s >>= 1) {
        #pragma unroll
        for (int ol = 0; ol < 4; ++ol)
            am[ol] = fmaxf(am[ol], __shfl_xor(am[ol], s, 64));
    }
    const int wave = t >> 6, lane = t & 63;
    if (lane == 0) {
        red[wave][0] = am[0]; red[wave][1] = am[1];
        red[wave][2] = am[2]; red[wave][3] = am[3];
    }
    __syncthreads();

    float4 bias4 = *(const float4*)&bias[o0];
    float bb[4] = {bias4.x, bias4.y, bias4.z, bias4.w};
    float add[4];
    #pragma unroll
    for (int ol = 0; ol < 4; ++ol) {
        float v = red[0][ol];
        #pragma unroll
        for (int w = 1; w < 8; ++w) v = fmaxf(v, red[w][ol]);
        add[ol] = v + bb[ol];
    }

    // ---- write the block's column-slice, once ----
    float4* out4 = (float4*)(out + (size_t)b * 1024 * 64);
    out4[r0 * 16 + og] = make_float4(c[0][0] + add[0], c[0][1] + add[1],
                                     c[0][2] + add[2], c[0][3] + add[3]);
    out4[r1 * 16 + og] = make_float4(c[1][0] + add[0], c[1][1] + add[1],
                                     c[1][2] + add[2], c[1][3] + add[3]);
}

extern "C" void kernel_launch(void* const* d_in, const int* in_sizes, int n_in,
                              void* d_out, int out_size, void* d_ws, size_t ws_size,
                              hipStream_t stream) {
    const float* x    = (const float*)d_in[0];
    const float* W    = (const float*)d_in[1];
    const float* bias = (const float*)d_in[2];
    float* out = (float*)d_out;

    pe_onepass<<<dim3(64), dim3(512), 0, stream>>>(x, W, bias, out);
}

// Round 5
// 16.701 us; speedup vs baseline: 3.3949x; 1.0930x over previous
//
#include <hip/hip_runtime.h>

// Single dispatch, no inter-block communication.
// Block (b, og) owns output columns o0=og*2, o0+1 for ALL 1024 rows of batch b.
//   amax[o] = max_n x[b,n,:]·W1[o,:]     (block-internal: shfl + tiny LDS tree)
//   out[b,m,o] = x[b,m,:]·W2[o,:] + amax[o] + bias[o]
// 1024 threads, thread t owns row t. 256 FMAs/thread.
__global__ __launch_bounds__(1024) void pe_onepass(const float* __restrict__ x,
                                                   const float* __restrict__ W,
                                                   const float* __restrict__ bias,
                                                   float* __restrict__ out) {
    __shared__ float red[16][2];

    const int t  = threadIdx.x;
    const int b  = blockIdx.x >> 5;
    const int og = blockIdx.x & 31;
    const int o0 = og << 1;

    const float4* x4  = (const float4*)(x + (size_t)b * 65536) + (size_t)t * 16;
    const float4* w10 = (const float4*)(W + (size_t)o0 * 128);  // col o0,  W1 half
    const float4* w20 = w10 + 16;                               // col o0,  W2 half
    const float4* w11 = w10 + 32;                               // col o0+1, W1 half
    const float4* w21 = w10 + 48;                               // col o0+1, W2 half

    float a0 = 0.f, a1 = 0.f, c0 = 0.f, c1 = 0.f;
    #pragma unroll
    for (int q = 0; q < 16; ++q) {
        float4 xq = x4[q];
        float4 u = w10[q], v = w20[q], s = w11[q], r = w21[q];   // wave-uniform -> s_load
        a0 += xq.x * u.x + xq.y * u.y + xq.z * u.z + xq.w * u.w;
        c0 += xq.x * v.x + xq.y * v.y + xq.z * v.z + xq.w * v.w;
        a1 += xq.x * s.x + xq.y * s.y + xq.z * s.z + xq.w * s.w;
        c1 += xq.x * r.x + xq.y * r.y + xq.z * r.z + xq.w * r.w;
    }

    // ---- block max over 1024 rows for the 2 columns ----
    float m0 = a0, m1 = a1;
    #pragma unroll
    for (int s = 32; s > 0; s >>= 1) {
        m0 = fmaxf(m0, __shfl_xor(m0, s, 64));
        m1 = fmaxf(m1, __shfl_xor(m1, s, 64));
    }
    if ((t & 63) == 0) { red[t >> 6][0] = m0; red[t >> 6][1] = m1; }
    __syncthreads();

    float add0 = red[0][0], add1 = red[0][1];
    #pragma unroll
    for (int w = 1; w < 16; ++w) {
        add0 = fmaxf(add0, red[w][0]);
        add1 = fmaxf(add1, red[w][1]);
    }
    add0 += bias[o0];
    add1 += bias[o0 + 1];

    *(float2*)&out[(size_t)b * 65536 + (size_t)t * 64 + o0] =
        make_float2(c0 + add0, c1 + add1);
}

extern "C" void kernel_launch(void* const* d_in, const int* in_sizes, int n_in,
                              void* d_out, int out_size, void* d_ws, size_t ws_size,
                              hipStream_t stream) {
    const float* x    = (const float*)d_in[0];
    const float* W    = (const float*)d_in[1];
    const float* bias = (const float*)d_in[2];
    float* out = (float*)d_out;

    pe_onepass<<<dim3(128), dim3(1024), 0, stream>>>(x, W, bias, out);
}

// Round 6
// 13.125 us; speedup vs baseline: 4.3197x; 1.2724x over previous
//
#include <hip/hip_runtime.h>

#define WPAD 68   // padded LDS row stride (floats)

// Two kernels, 256 blocks x 512 threads each, 2 waves/SIMD.
// Thread layout: r = t>>5 (row 0..15), og = (t>>1)&15 (o-quad), kh = t&1 (k-half).
// Per thread: 8 q-iters x (1 x-quad + 4 W-quads) LDS reads, 128 FMAs.
// k-halves summed via shfl_xor(1); K1 row-pairs maxed via shfl_xor(32).

__global__ __launch_bounds__(512) void pe_k1(const float* __restrict__ x,
                                             const float* __restrict__ W,
                                             float* __restrict__ wsmax) {
    __shared__ float Wt[64 * WPAD];   // Wt[k*WPAD+o] = W1[o][k]
    __shared__ float xs[16 * WPAD];
    __shared__ float red[8 * 64];

    const int t  = threadIdx.x;
    const int b  = blockIdx.x >> 6;
    const int ch = blockIdx.x & 63;
    const int m0 = ch << 4;

    // stage W1^T (16 KB): 1024 float4 over 512 threads
    const float4* W4 = (const float4*)W;          // W row = 32 float4
    #pragma unroll
    for (int i = 0; i < 2; ++i) {
        int id = t + 512 * i;
        int o = id >> 4, q = id & 15;
        float4 w = W4[o * 32 + q];                // W1 half
        Wt[(4 * q + 0) * WPAD + o] = w.x;
        Wt[(4 * q + 1) * WPAD + o] = w.y;
        Wt[(4 * q + 2) * WPAD + o] = w.z;
        Wt[(4 * q + 3) * WPAD + o] = w.w;
    }
    if (t < 256) {                                // stage 16 rows of x (4 KB)
        const float4* x4 = (const float4*)(x + ((size_t)b * 1024 + m0) * 64);
        float4 xv = x4[t];
        *(float4*)&xs[(t >> 4) * WPAD + 4 * (t & 15)] = xv;
    }
    __syncthreads();

    const int r  = t >> 5;
    const int og = (t >> 1) & 15;
    const int kh = t & 1;
    const float* xr = &xs[r * WPAD + kh * 32];
    const int k0 = kh * 32;

    float ax = 0.f, ay = 0.f, az = 0.f, aw = 0.f;
    #pragma unroll
    for (int q = 0; q < 8; ++q) {
        float4 xq = *(const float4*)&xr[4 * q];
        float4 w0 = *(const float4*)&Wt[(k0 + 4 * q + 0) * WPAD + og * 4];
        float4 w1 = *(const float4*)&Wt[(k0 + 4 * q + 1) * WPAD + og * 4];
        float4 w2 = *(const float4*)&Wt[(k0 + 4 * q + 2) * WPAD + og * 4];
        float4 w3 = *(const float4*)&Wt[(k0 + 4 * q + 3) * WPAD + og * 4];
        ax += xq.x * w0.x + xq.y * w1.x + xq.z * w2.x + xq.w * w3.x;
        ay += xq.x * w0.y + xq.y * w1.y + xq.z * w2.y + xq.w * w3.y;
        az += xq.x * w0.z + xq.y * w1.z + xq.z * w2.z + xq.w * w3.z;
        aw += xq.x * w0.w + xq.y * w1.w + xq.z * w2.w + xq.w * w3.w;
    }
    // sum the two k-halves (lane bit0)
    ax += __shfl_xor(ax, 1); ay += __shfl_xor(ay, 1);
    az += __shfl_xor(az, 1); aw += __shfl_xor(aw, 1);
    // max over the wave's row pair (lane bit5)
    ax = fmaxf(ax, __shfl_xor(ax, 32)); ay = fmaxf(ay, __shfl_xor(ay, 32));
    az = fmaxf(az, __shfl_xor(az, 32)); aw = fmaxf(aw, __shfl_xor(aw, 32));

    if ((t & 33) == 0)                            // one lane per (wave, og)
        *(float4*)&red[(t >> 6) * 64 + og * 4] = make_float4(ax, ay, az, aw);
    __syncthreads();

    if (t < 64) {                                 // max over 8 wave-partials
        float v = red[t];
        #pragma unroll
        for (int w = 1; w < 8; ++w) v = fmaxf(v, red[w * 64 + t]);
        wsmax[((size_t)(b << 6) + ch) * 64 + t] = v;
    }
}

__global__ __launch_bounds__(512) void pe_k2(const float* __restrict__ x,
                                             const float* __restrict__ W,
                                             const float* __restrict__ bias,
                                             const float* __restrict__ wsmax,
                                             float* __restrict__ out) {
    __shared__ float Wt[64 * WPAD];   // Wt[k*WPAD+o] = W2[o][k]
    __shared__ float xs[16 * WPAD];
    __shared__ float amx[8 * 64];
    __shared__ float addv[64];

    const int t  = threadIdx.x;
    const int b  = blockIdx.x >> 6;
    const int ch = blockIdx.x & 63;
    const int m0 = ch << 4;

    const float4* W4 = (const float4*)W;
    #pragma unroll
    for (int i = 0; i < 2; ++i) {
        int id = t + 512 * i;
        int o = id >> 4, q = id & 15;
        float4 w = W4[o * 32 + 16 + q];           // W2 half
        Wt[(4 * q + 0) * WPAD + o] = w.x;
        Wt[(4 * q + 1) * WPAD + o] = w.y;
        Wt[(4 * q + 2) * WPAD + o] = w.z;
        Wt[(4 * q + 3) * WPAD + o] = w.w;
    }
    if (t < 256) {
        const float4* x4 = (const float4*)(x + ((size_t)b * 1024 + m0) * 64);
        float4 xv = x4[t];
        *(float4*)&xs[(t >> 4) * WPAD + 4 * (t & 15)] = xv;
    }
    // parallel amax gather: thread t -> col o = t&63, segment g = t>>6 (8 segs)
    {
        const int o = t & 63, g = t >> 6;
        const float* wp = wsmax + (size_t)b * 4096 + o;
        float v = wp[(size_t)g * 64];
        #pragma unroll
        for (int s = 1; s < 8; ++s) v = fmaxf(v, wp[(size_t)(g + 8 * s) * 64]);
        amx[g * 64 + o] = v;
    }
    __syncthreads();
    if (t < 64) {
        float v = amx[t];
        #pragma unroll
        for (int w = 1; w < 8; ++w) v = fmaxf(v, amx[w * 64 + t]);
        addv[t] = v + bias[t];
    }
    // GEMM overlaps the addv tree; sync #2 below before addv is read.
    const int r  = t >> 5;
    const int og = (t >> 1) & 15;
    const int kh = t & 1;
    const float* xr = &xs[r * WPAD + kh * 32];
    const int k0 = kh * 32;

    float cx = 0.f, cy = 0.f, cz = 0.f, cw = 0.f;
    #pragma unroll
    for (int q = 0; q < 8; ++q) {
        float4 xq = *(const float4*)&xr[4 * q];
        float4 w0 = *(const float4*)&Wt[(k0 + 4 * q + 0) * WPAD + og * 4];
        float4 w1 = *(const float4*)&Wt[(k0 + 4 * q + 1) * WPAD + og * 4];
        float4 w2 = *(const float4*)&Wt[(k0 + 4 * q + 2) * WPAD + og * 4];
        float4 w3 = *(const float4*)&Wt[(k0 + 4 * q + 3) * WPAD + og * 4];
        cx += xq.x * w0.x + xq.y * w1.x + xq.z * w2.x + xq.w * w3.x;
        cy += xq.x * w0.y + xq.y * w1.y + xq.z * w2.y + xq.w * w3.y;
        cz += xq.x * w0.z + xq.y * w1.z + xq.z * w2.z + xq.w * w3.z;
        cw += xq.x * w0.w + xq.y * w1.w + xq.z * w2.w + xq.w * w3.w;
    }
    cx += __shfl_xor(cx, 1); cy += __shfl_xor(cy, 1);
    cz += __shfl_xor(cz, 1); cw += __shfl_xor(cw, 1);
    __syncthreads();

    if (kh == 0) {
        float4 add = *(const float4*)&addv[og * 4];
        *(float4*)&out[((size_t)b * 1024 + m0 + r) * 64 + og * 4] =
            make_float4(cx + add.x, cy + add.y, cz + add.z, cw + add.w);
    }
}

extern "C" void kernel_launch(void* const* d_in, const int* in_sizes, int n_in,
                              void* d_out, int out_size, void* d_ws, size_t ws_size,
                              hipStream_t stream) {
    const float* x    = (const float*)d_in[0];
    const float* W    = (const float*)d_in[1];
    const float* bias = (const float*)d_in[2];
    float* out   = (float*)d_out;
    float* wsmax = (float*)d_ws;   // 4*64*64*4 = 64 KiB used

    pe_k1<<<4 * 64, 512, 0, stream>>>(x, W, wsmax);
    pe_k2<<<4 * 64, 512, 0, stream>>>(x, W, bias, wsmax, out);
}

// Round 7
// 13.015 us; speedup vs baseline: 4.3564x; 1.0085x over previous
//
#include <hip/hip_runtime.h>

#define WPAD 68   // transposed-W LDS row stride (floats); rows 16B-aligned

// Two kernels, 256 blocks x 256 threads (1 block/CU).
// Layout: r = t>>4 (row 0..15), og = t&15 (o-quad). The 16 lanes sharing a
// row read identical x addresses -> global broadcast; x is prefetched to
// registers BEFORE the staging barrier so its latency hides under W staging.

__global__ __launch_bounds__(256) void pe_k1(const float* __restrict__ x,
                                             const float* __restrict__ W,
                                             float* __restrict__ wsmax) {
    __shared__ float Wt[64 * WPAD];   // Wt[k*WPAD+o] = W1[o][k]
    __shared__ float red[4 * 64];

    const int t  = threadIdx.x;
    const int b  = blockIdx.x >> 6;
    const int ch = blockIdx.x & 63;
    const int m0 = ch << 4;
    const int r  = t >> 4;
    const int og = t & 15;

    // prefetch this thread's x row (16 quads) -> registers (broadcast loads)
    const float4* xr = (const float4*)(x + ((size_t)b * 1024 + m0 + r) * 64);
    float4 xq[16];
    #pragma unroll
    for (int q = 0; q < 16; ++q) xq[q] = xr[q];

    // stage W1^T (16 KB)
    const float4* W4 = (const float4*)W;          // W row = 32 float4
    #pragma unroll
    for (int i = 0; i < 4; ++i) {
        int id = t + 256 * i;
        int o = id >> 4, q = id & 15;
        float4 w = W4[o * 32 + q];                // W1 half
        Wt[(4 * q + 0) * WPAD + o] = w.x;
        Wt[(4 * q + 1) * WPAD + o] = w.y;
        Wt[(4 * q + 2) * WPAD + o] = w.z;
        Wt[(4 * q + 3) * WPAD + o] = w.w;
    }
    __syncthreads();

    float ax = 0.f, ay = 0.f, az = 0.f, aw = 0.f;
    #pragma unroll
    for (int q = 0; q < 16; ++q) {
        float4 xv = xq[q];
        float4 w0 = *(const float4*)&Wt[(4 * q + 0) * WPAD + og * 4];
        float4 w1 = *(const float4*)&Wt[(4 * q + 1) * WPAD + og * 4];
        float4 w2 = *(const float4*)&Wt[(4 * q + 2) * WPAD + og * 4];
        float4 w3 = *(const float4*)&Wt[(4 * q + 3) * WPAD + og * 4];
        ax += xv.x * w0.x + xv.y * w1.x + xv.z * w2.x + xv.w * w3.x;
        ay += xv.x * w0.y + xv.y * w1.y + xv.z * w2.y + xv.w * w3.y;
        az += xv.x * w0.z + xv.y * w1.z + xv.z * w2.z + xv.w * w3.z;
        aw += xv.x * w0.w + xv.y * w1.w + xv.z * w2.w + xv.w * w3.w;
    }

    // max over the wave's 4 rows (lane bits 4,5)
    ax = fmaxf(ax, __shfl_xor(ax, 16)); ay = fmaxf(ay, __shfl_xor(ay, 16));
    az = fmaxf(az, __shfl_xor(az, 16)); aw = fmaxf(aw, __shfl_xor(aw, 16));
    ax = fmaxf(ax, __shfl_xor(ax, 32)); ay = fmaxf(ay, __shfl_xor(ay, 32));
    az = fmaxf(az, __shfl_xor(az, 32)); aw = fmaxf(aw, __shfl_xor(aw, 32));

    if ((t & 48) == 0)                            // one lane-row per wave
        *(float4*)&red[(t >> 6) * 64 + og * 4] = make_float4(ax, ay, az, aw);
    __syncthreads();

    if (t < 64) {
        float v = fmaxf(fmaxf(red[t], red[64 + t]),
                        fmaxf(red[128 + t], red[192 + t]));
        wsmax[((size_t)(b << 6) + ch) * 64 + t] = v;
    }
}

__global__ __launch_bounds__(256) void pe_k2(const float* __restrict__ x,
                                             const float* __restrict__ W,
                                             const float* __restrict__ bias,
                                             const float* __restrict__ wsmax,
                                             float* __restrict__ out) {
    __shared__ float Wt[64 * WPAD];   // Wt[k*WPAD+o] = W2[o][k]
    __shared__ float amx[4 * 64];
    __shared__ float addv[64];

    const int t  = threadIdx.x;
    const int b  = blockIdx.x >> 6;
    const int ch = blockIdx.x & 63;
    const int m0 = ch << 4;
    const int r  = t >> 4;
    const int og = t & 15;

    // amax gather first: L2 latency overlaps everything below.
    // thread t -> col o = t&63, segment g = t>>6; coalesced 256B rows.
    float gv;
    {
        const int o = t & 63, g = t >> 6;
        const float* wp = wsmax + (size_t)b * 4096 + o;
        gv = wp[(size_t)g * 64];
        #pragma unroll
        for (int s = 1; s < 16; ++s) gv = fmaxf(gv, wp[(size_t)(g + 4 * s) * 64]);
    }

    // prefetch x row quads -> registers
    const float4* xr = (const float4*)(x + ((size_t)b * 1024 + m0 + r) * 64);
    float4 xq[16];
    #pragma unroll
    for (int q = 0; q < 16; ++q) xq[q] = xr[q];

    // stage W2^T
    const float4* W4 = (const float4*)W;
    #pragma unroll
    for (int i = 0; i < 4; ++i) {
        int id = t + 256 * i;
        int o = id >> 4, q = id & 15;
        float4 w = W4[o * 32 + 16 + q];           // W2 half
        Wt[(4 * q + 0) * WPAD + o] = w.x;
        Wt[(4 * q + 1) * WPAD + o] = w.y;
        Wt[(4 * q + 2) * WPAD + o] = w.z;
        Wt[(4 * q + 3) * WPAD + o] = w.w;
    }
    amx[(t >> 6) * 64 + (t & 63)] = gv;
    __syncthreads();

    if (t < 64)
        addv[t] = fmaxf(fmaxf(amx[t], amx[64 + t]),
                        fmaxf(amx[128 + t], amx[192 + t])) + bias[t];
    // GEMM overlaps the addv tree; barrier below before addv is read.
    float cx = 0.f, cy = 0.f, cz = 0.f, cw = 0.f;
    #pragma unroll
    for (int q = 0; q < 16; ++q) {
        float4 xv = xq[q];
        float4 w0 = *(const float4*)&Wt[(4 * q + 0) * WPAD + og * 4];
        float4 w1 = *(const float4*)&Wt[(4 * q + 1) * WPAD + og * 4];
        float4 w2 = *(const float4*)&Wt[(4 * q + 2) * WPAD + og * 4];
        float4 w3 = *(const float4*)&Wt[(4 * q + 3) * WPAD + og * 4];
        cx += xv.x * w0.x + xv.y * w1.x + xv.z * w2.x + xv.w * w3.x;
        cy += xv.x * w0.y + xv.y * w1.y + xv.z * w2.y + xv.w * w3.y;
        cz += xv.x * w0.z + xv.y * w1.z + xv.z * w2.z + xv.w * w3.z;
        cw += xv.x * w0.w + xv.y * w1.w + xv.z * w2.w + xv.w * w3.w;
    }
    __syncthreads();

    float4 add = *(const float4*)&addv[og * 4];
    *(float4*)&out[((size_t)b * 1024 + m0 + r) * 64 + og * 4] =
        make_float4(cx + add.x, cy + add.y, cz + add.z, cw + add.w);
}

extern "C" void kernel_launch(void* const* d_in, const int* in_sizes, int n_in,
                              void* d_out, int out_size, void* d_ws, size_t ws_size,
                              hipStream_t stream) {
    const float* x    = (const float*)d_in[0];
    const float* W    = (const float*)d_in[1];
    const float* bias = (const float*)d_in[2];
    float* out   = (float*)d_out;
    float* wsmax = (float*)d_ws;   // 4*64*64*4 = 64 KiB used

    pe_k1<<<4 * 64, 256, 0, stream>>>(x, W, wsmax);
    pe_k2<<<4 * 64, 256, 0, stream>>>(x, W, bias, wsmax, out);
}